// Round 9
// baseline (712.335 us; speedup 1.0000x reference)
//
#include <hip/hip_runtime.h>
#include <hip/hip_bf16.h>

#define Nn 200000
#define Cc 1000
#define Dd 256
#define PAD 16        // counter padding (one per 64B line)
#define NCH3 6250     // Nn / 32
#define GBLK3 1250    // gemm grid: 1250 blocks x 5 chunks

typedef float f32x16 __attribute__((ext_vector_type(16)));
typedef short bf16x8 __attribute__((ext_vector_type(8)));

#define LOG2E  1.4426950408889634f
#define LOG2E2 2.8853900817779268f

__device__ __forceinline__ unsigned int f2bf(float x){
    union { float f; unsigned int u; } c; c.f = x;
    unsigned int u = c.u;
    u += 0x7fffu + ((u >> 16) & 1u);   // round-to-nearest-even
    return u >> 16;
}
__device__ __forceinline__ float bf2f(unsigned short b){
    union { unsigned int u; float f; } c; c.u = ((unsigned int)b) << 16;
    return c.f;
}
__device__ __forceinline__ float rcp_(float x){ return __builtin_amdgcn_rcpf(x); }

// ---------------- prep: W fragment tables (MFMA 32x32x16 operand order) + zero hist ----------------
// slot ((ct*16 + kk)*64 + lane): lane holds W[k0..k0+7][col], col = ct*32+(lane&31),
// k0 = kk*16 + (lane>>5)*8.  ct 0..7 = Wk, ct 8..15 = H1w (tables contiguous).
__global__ void k_prep(const float* __restrict__ Wk, const float* __restrict__ H1w,
                       unsigned short* __restrict__ wfragK, unsigned short* __restrict__ wfragH,
                       int* __restrict__ hist){
    int t = blockIdx.x*256 + threadIdx.x;       // 64 x 256 = 16384
    if (t < Cc*PAD) hist[t] = 0;
    int arr = t >> 13;
    int s   = t & 8191;
    int ct  = s >> 10;
    int kk  = (s >> 6) & 15;
    int l   = s & 63;
    int col = ct*32 + (l & 31);
    int k0  = kk*16 + (l >> 5)*8;
    const float* W = arr ? H1w : Wk;
    unsigned short* dst = (arr ? wfragH : wfragK) + (size_t)s*8;
    #pragma unroll
    for (int e = 0; e < 8; ++e) dst[e] = (unsigned short)f2bf(W[(size_t)(k0+e)*Dd + col]);
}

// ---------------- per-cluster precompute (1000 blocks) + node histogram fused ----------------
__global__ __launch_bounds__(256)
void k_cluster_prep(const float* __restrict__ g, const float* __restrict__ Wq,
                    const float* __restrict__ b_attn,
                    const float* __restrict__ Ws, const float* __restrict__ bs,
                    const float* __restrict__ G1w, const float* __restrict__ G1b,
                    const float* __restrict__ H1b,
                    const int* __restrict__ seg, int* __restrict__ hist,
                    float* __restrict__ qb, float* __restrict__ h_trans,
                    float* __restrict__ cterm){
    int c = blockIdx.x, d = threadIdx.x;
    int gi = c*256 + d;
    if (gi < Nn) atomicAdd(&hist[seg[gi]*PAD], 1);
    __shared__ float gL[Dd], htL[Dd];
    gL[d] = g[(size_t)c*Dd + d];
    __syncthreads();
    float aq = b_attn[d], as = bs[d];
    #pragma unroll 4
    for (int k = 0; k < Dd; ++k){
        float gv = gL[k];
        aq = fmaf(gv, Wq[k*Dd + d], aq);
        as = fmaf(gv, Ws[k*Dd + d], as);
    }
    qb[(size_t)c*Dd + d] = aq;
    float ht = tanhf(as);
    h_trans[(size_t)c*Dd + d] = ht;
    htL[d] = ht;
    __syncthreads();
    float ac = H1b[d] + G1b[d];
    #pragma unroll 4
    for (int k = 0; k < Dd; ++k) ac = fmaf(htL[k], G1w[k*Dd + d], ac);
    cterm[(size_t)c*Dd + d] = ac;
}

// ---------------- counting sort: scan + scatter (padded counters) ----------------
__global__ void k_scan(const int* __restrict__ hist, int* __restrict__ offs, int* __restrict__ cursor){
    __shared__ int sc[1024];
    int t = threadIdx.x;
    int v = (t < Cc) ? hist[t*PAD] : 0;
    sc[t] = v;
    __syncthreads();
    for (int off = 1; off < 1024; off <<= 1){
        int add = (t >= off) ? sc[t - off] : 0;
        __syncthreads();
        sc[t] += add;
        __syncthreads();
    }
    if (t < Cc){
        int excl = sc[t] - v;
        offs[t] = excl;
        cursor[t*PAD] = excl;
    }
}
__global__ void k_scatter(const int* __restrict__ seg, int* __restrict__ cursor, int* __restrict__ order){
    int i = blockIdx.x*256 + threadIdx.x;
    if (i < Nn){
        int p = atomicAdd(&cursor[seg[i]*PAD], 1);
        order[p] = i;
    }
}

// ================= fused score+merge GEMM, swapped operands (D: row=node, col=lane) =================
// 1250 blocks x 512 threads x 5 chunks of 32 nodes. W (both Wk ct=w and H1w ct=w+8) in REGISTERS,
// loaded once per block. LDS = 16KB A-tile only. k-loop: 1 ds_read + 2 MFMA, zero VMEM.
// Epilogues: scalar dword accesses, 64 lanes = 2 rows x 128B contiguous -> 4 lines/instr.
__global__ __launch_bounds__(512, 2)
void k_gemm3(const float* __restrict__ h, const unsigned short* __restrict__ wfrag,
             const int* __restrict__ seg, const float* __restrict__ qb,
             const float* __restrict__ w_score, const float* __restrict__ b_score,
             const float* __restrict__ cterm, const float* __restrict__ h_trans,
             float* __restrict__ e, float* __restrict__ out){
    __shared__ __align__(16) char Al[16384];    // 32 nodes x 512B bf16, XOR-swizzled
    __shared__ float sPart[32][8];
    __shared__ int segL[32];

    int tid = threadIdx.x;
    int w = tid >> 6, l = tid & 63;
    int lCol = l & 31, hiK = l >> 5;

    // ---- W fragments once per block: score tile ct=w, merge tile ct=w+8 ----
    const char* wfb = reinterpret_cast<const char*>(wfrag);
    bf16x8 wS[16], wM[16];
    #pragma unroll
    for (int kk = 0; kk < 16; ++kk){
        wS[kk] = *reinterpret_cast<const bf16x8*>(wfb + (size_t)(( w   *16 + kk)*64 + l)*16);
        wM[kk] = *reinterpret_cast<const bf16x8*>(wfb + (size_t)(((w+8)*16 + kk)*64 + l)*16);
    }
    float wsc = w_score[w*32 + lCol];
    float bsc = b_score[0];

    int ch = blockIdx.x;
    // preload chunk 0 (h rows + seg)
    float4 v[4];
    {
        const float4* hv = reinterpret_cast<const float4*>(h + (size_t)ch*32*Dd);
        #pragma unroll
        for (int j = 0; j < 4; ++j) v[j] = hv[j*512 + tid];
    }
    int myseg = (tid < 32) ? seg[ch*32 + tid] : 0;

    for (int it = 0; it < 5; ++it, ch += GBLK3){
        int rowBase = ch*32;
        // ---- write A tile (bf16 pack, swizzled) ----
        if (tid < 32) segL[tid] = myseg;
        #pragma unroll
        for (int j = 0; j < 4; ++j){
            int f = j*512 + tid;
            int row = f >> 6;
            unsigned long long pk = (unsigned long long)f2bf(v[j].x)
                                  | ((unsigned long long)f2bf(v[j].y) << 16)
                                  | ((unsigned long long)f2bf(v[j].z) << 32)
                                  | ((unsigned long long)f2bf(v[j].w) << 48);
            int byte = (row*512 + (f & 63)*8) ^ ((row & 15) << 4);
            *reinterpret_cast<unsigned long long*>(Al + byte) = pk;
        }
        __syncthreads();   // A ready

        // ---- prefetch next chunk into regs (hides under k-loop + epilogue) ----
        if (it < 4){
            const float4* hn = reinterpret_cast<const float4*>(h + (size_t)(ch + GBLK3)*32*Dd);
            #pragma unroll
            for (int j = 0; j < 4; ++j) v[j] = hn[j*512 + tid];
            if (tid < 32) myseg = seg[(ch + GBLK3)*32 + tid];
        }

        // ---- k-loop: LDS-only; h as A-operand (row=node), W as B-operand (col=lane) ----
        f32x16 aS, aM;
        #pragma unroll
        for (int i = 0; i < 16; ++i){ aS[i] = 0.f; aM[i] = 0.f; }
        int hOff = lCol*512;               // here lane&31 = node for the A fragment
        int swzK = (lCol & 15) << 4;
        #pragma unroll
        for (int kk = 0; kk < 16; ++kk){
            bf16x8 hF = *reinterpret_cast<const bf16x8*>(Al + ((hOff + kk*32 + hiK*16) ^ swzK));
            aS = __builtin_amdgcn_mfma_f32_32x32x16_bf16(hF, wS[kk], aS, 0, 0, 0);
            aM = __builtin_amdgcn_mfma_f32_32x32x16_bf16(hF, wM[kk], aM, 0, 0, 0);
        }

        // rows this lane-half covers: r = (i&3) + 8*(i>>2) + 4*hiK
        int sg[16];
        #pragma unroll
        for (int i = 0; i < 16; ++i) sg[i] = segL[(i&3) + 8*(i>>2) + 4*hiK];

        // ---- score epilogue: p(row) = sum_cols tanh(y + qb[seg])*w_score ----
        #pragma unroll
        for (int i = 0; i < 16; ++i){
            int r = (i&3) + 8*(i>>2) + 4*hiK;
            float q = qb[(size_t)sg[i]*Dd + w*32 + lCol];
            float t = exp2f(LOG2E2*(aS[i] + q));
            float p = (t - 1.f)*rcp_(t + 1.f)*wsc;
            p += __shfl_xor(p, 1);
            p += __shfl_xor(p, 2);
            p += __shfl_xor(p, 4);
            p += __shfl_xor(p, 8);
            p += __shfl_xor(p, 16);
            if (lCol == 0) sPart[r][w] = p;
        }

        // ---- merge epilogue: z = sigmoid(y + cterm[seg]); out = h + z*(h_trans[seg]-h) ----
        #pragma unroll
        for (int i = 0; i < 16; ++i){
            int r = (i&3) + 8*(i>>2) + 4*hiK;
            size_t tb = (size_t)sg[i]*Dd + w*32 + lCol;
            float c4 = cterm[tb];
            float t4 = h_trans[tb];
            unsigned short hb = *reinterpret_cast<const unsigned short*>(
                Al + ((r*512 + (w*32 + lCol)*2) ^ ((r & 15) << 4)));
            float hval = bf2f(hb);
            float z = rcp_(1.f + exp2f(-LOG2E*(aM[i] + c4)));
            out[(size_t)(rowBase + r)*Dd + w*32 + lCol] = fmaf(z, t4 - hval, hval);
        }
        __syncthreads();   // sPart complete; Al free
        if (tid < 32){
            float s = sPart[tid][0] + sPart[tid][1] + sPart[tid][2] + sPart[tid][3]
                    + sPart[tid][4] + sPart[tid][5] + sPart[tid][6] + sPart[tid][7] + bsc;
            e[rowBase + tid] = exp2f(LOG2E * s);   // unshifted exp: |s| small, ratio == ref
        }
        __syncthreads();   // e-read of sPart done before next iter's score writes
    }
}

// ---------------- per-cluster ctx partials: 4 chunk-blocks per cluster, no atomics ----------------
__global__ __launch_bounds__(256)
void k_ctx(const float* __restrict__ h, const float* __restrict__ e,
           const int* __restrict__ order, const int* __restrict__ hist,
           const int* __restrict__ offs,
           float* __restrict__ ctxPart, float* __restrict__ denPart){
    int b = blockIdx.x;
    int c = b >> 2, q = b & 3;
    int cnt = hist[c*PAD], start0 = offs[c];
    int c0 = (cnt * q) >> 2, c1 = (cnt * (q+1)) >> 2;
    int n = c1 - c0;
    int start = start0 + c0;
    int t = threadIdx.x;
    __shared__ int idxL[512];
    __shared__ float eL[512];
    __shared__ float redL[4][256];
    __shared__ float dsum[4];
    int r4 = t >> 6;
    int col4 = (t & 63) << 2;
    float ax = 0.f, ay = 0.f, az = 0.f, aw = 0.f;
    float dpart = 0.f;
    for (int base = 0; base < n; base += 512){
        int m = min(512, n - base);
        for (int i = t; i < m; i += 256){
            int nd = order[start + base + i];
            idxL[i] = nd;
            float ev = e[nd];
            eL[i] = ev;
            dpart += ev;
        }
        __syncthreads();
        #pragma unroll 4
        for (int i = r4; i < m; i += 4){
            float ev = eL[i];
            float4 hv = *reinterpret_cast<const float4*>(h + (size_t)idxL[i]*Dd + col4);
            ax = fmaf(ev, hv.x, ax);
            ay = fmaf(ev, hv.y, ay);
            az = fmaf(ev, hv.z, az);
            aw = fmaf(ev, hv.w, aw);
        }
        __syncthreads();
    }
    *reinterpret_cast<float4*>(&redL[r4][col4]) = (float4){ax, ay, az, aw};
    #pragma unroll
    for (int off = 1; off < 64; off <<= 1) dpart += __shfl_xor(dpart, off);
    if ((t & 63) == 0) dsum[r4] = dpart;
    __syncthreads();
    if (t < 256){
        float s = redL[0][t] + redL[1][t] + redL[2][t] + redL[3][t];
        ctxPart[((size_t)c*4 + q)*Dd + t] = s;
    }
    if (t == 0) denPart[b] = dsum[0] + dsum[1] + dsum[2] + dsum[3];
}

// ---------------- virtual-node side (1 cluster/block) ----------------
__global__ __launch_bounds__(256)
void k_vn(const float* __restrict__ ctxPart, const float* __restrict__ denPart,
          const float* __restrict__ g_hat,
          const float* __restrict__ Wv, const float* __restrict__ bv,
          const float* __restrict__ H2w, const float* __restrict__ H2b,
          const float* __restrict__ G2w, const float* __restrict__ G2b,
          float* __restrict__ out){
    int c = blockIdx.x, d = threadIdx.x;
    __shared__ float cL[Dd], gtL[Dd], ghL[Dd];
    float den = denPart[c*4] + denPart[c*4+1] + denPart[c*4+2] + denPart[c*4+3];
    float inv = (den > 0.f) ? 1.f/den : 0.f;
    float num = ctxPart[((size_t)c*4 + 0)*Dd + d] + ctxPart[((size_t)c*4 + 1)*Dd + d]
              + ctxPart[((size_t)c*4 + 2)*Dd + d] + ctxPart[((size_t)c*4 + 3)*Dd + d];
    cL[d]  = num * inv;
    ghL[d] = g_hat[(size_t)c*Dd + d];
    __syncthreads();
    float a1 = bv[d];
    #pragma unroll 4
    for (int k = 0; k < Dd; ++k) a1 = fmaf(cL[k], Wv[k*Dd + d], a1);
    float gt = tanhf(a1);
    gtL[d] = gt;
    __syncthreads();
    float a2 = H2b[d] + G2b[d];
    #pragma unroll 4
    for (int k = 0; k < Dd; ++k){
        a2 = fmaf(gtL[k], H2w[k*Dd + d], a2);
        a2 = fmaf(ghL[k], G2w[k*Dd + d], a2);
    }
    float z = 1.f / (1.f + expf(-a2));
    out[(size_t)(Nn + c)*Dd + d] = (1.f - z)*gt + z*ghL[d];
}

extern "C" void kernel_launch(void* const* d_in, const int* in_sizes, int n_in,
                              void* d_out, int out_size, void* d_ws, size_t ws_size,
                              hipStream_t stream){
    const float* h       = (const float*)d_in[0];
    const float* g       = (const float*)d_in[1];
    const float* g_hat   = (const float*)d_in[2];
    const int*   seg     = (const int*)  d_in[3];
    const float* Wq      = (const float*)d_in[4];
    const float* Wk      = (const float*)d_in[5];
    const float* b_attn  = (const float*)d_in[6];
    const float* w_score = (const float*)d_in[7];
    const float* b_score = (const float*)d_in[8];
    const float* Wv      = (const float*)d_in[9];
    const float* bv      = (const float*)d_in[10];
    const float* Ws      = (const float*)d_in[11];
    const float* bs      = (const float*)d_in[12];
    const float* H1w     = (const float*)d_in[13];
    const float* H1b     = (const float*)d_in[14];
    const float* G1w     = (const float*)d_in[15];
    const float* G1b     = (const float*)d_in[16];
    const float* H2w     = (const float*)d_in[17];
    const float* H2b     = (const float*)d_in[18];
    const float* G2w     = (const float*)d_in[19];
    const float* G2b     = (const float*)d_in[20];
    float* out = (float*)d_out;

    char* ws = (char*)d_ws;
    unsigned short* wfragK = (unsigned short*)(ws + 0);      //   131,072 B  (ct 0..7)
    unsigned short* wfragH = (unsigned short*)(ws + 131072); //   131,072 B  (ct 8..15, contiguous)
    float* qb      = (float*)(ws +  262144);                 // 1,024,000 B
    float* h_trans = (float*)(ws + 1286144);                 // 1,024,000 B
    float* cterm   = (float*)(ws + 2310144);                 // 1,024,000 B
    float* e       = (float*)(ws + 3334144);                 //   800,000 B
    int*   order   = (int*)  (ws + 4134144);                 //   800,000 B
    int*   hist    = (int*)  (ws + 4934144);                 //    64,000 B (padded x16)
    int*   offs    = (int*)  (ws + 4998144);                 //     4,000 B
    int*   cursor  = (int*)  (ws + 5002144);                 //    64,000 B (padded x16)
    float* ctxPart = (float*)(ws + 5066144);                 // 4,096,000 B
    float* denPart = (float*)(ws + 9162144);                 //    16,000 B

    hipLaunchKernelGGL(k_prep, dim3(64), dim3(256), 0, stream, Wk, H1w, wfragK, wfragH, hist);
    hipLaunchKernelGGL(k_cluster_prep, dim3(Cc), dim3(256), 0, stream,
                       g, Wq, b_attn, Ws, bs, G1w, G1b, H1b, seg, hist, qb, h_trans, cterm);
    hipLaunchKernelGGL(k_scan, dim3(1), dim3(1024), 0, stream, hist, offs, cursor);
    hipLaunchKernelGGL(k_scatter, dim3((Nn + 255)/256), dim3(256), 0, stream, seg, cursor, order);
    hipLaunchKernelGGL(k_gemm3, dim3(GBLK3), dim3(512), 0, stream,
                       h, wfragK, seg, qb, w_score, b_score, cterm, h_trans, e, out);
    hipLaunchKernelGGL(k_ctx, dim3(Cc*4), dim3(256), 0, stream, h, e, order, hist, offs, ctxPart, denPart);
    hipLaunchKernelGGL(k_vn, dim3(Cc), dim3(256), 0, stream,
                       ctxPart, denPart, g_hat, Wv, bv, H2w, H2b, G2w, G2b, out);
}

// Round 10
// 364.406 us; speedup vs baseline: 1.9548x; 1.9548x over previous
//
#include <hip/hip_runtime.h>
#include <hip/hip_bf16.h>

#define Nn 200000
#define Cc 1000
#define Dd 256
#define PAD 16        // counter padding (one per 64B line)
#define NCH4 6250     // Nn / 32 chunks, one per block

typedef float f32x16 __attribute__((ext_vector_type(16)));
typedef short bf16x8 __attribute__((ext_vector_type(8)));

#define LOG2E  1.4426950408889634f
#define LOG2E2 2.8853900817779268f

__device__ __forceinline__ unsigned int f2bf(float x){
    union { float f; unsigned int u; } c; c.f = x;
    unsigned int u = c.u;
    u += 0x7fffu + ((u >> 16) & 1u);   // round-to-nearest-even
    return u >> 16;
}
__device__ __forceinline__ float bf2f(unsigned short b){
    union { unsigned int u; float f; } c; c.u = ((unsigned int)b) << 16;
    return c.f;
}
__device__ __forceinline__ float rcp_(float x){ return __builtin_amdgcn_rcpf(x); }

// ---------------- prep: W fragment tables (MFMA 32x32x16 operand order) + zero hist ----------------
// slot ((ct*16 + kk)*64 + lane): lane holds W[k0..k0+7][col], col = ct*32+(lane&31),
// k0 = kk*16 + (lane>>5)*8.  ct 0..7 = Wk, ct 8..15 = H1w (tables contiguous).
__global__ void k_prep(const float* __restrict__ Wk, const float* __restrict__ H1w,
                       unsigned short* __restrict__ wfragK, unsigned short* __restrict__ wfragH,
                       int* __restrict__ hist){
    int t = blockIdx.x*256 + threadIdx.x;       // 64 x 256 = 16384
    if (t < Cc*PAD) hist[t] = 0;
    int arr = t >> 13;
    int s   = t & 8191;
    int ct  = s >> 10;
    int kk  = (s >> 6) & 15;
    int l   = s & 63;
    int col = ct*32 + (l & 31);
    int k0  = kk*16 + (l >> 5)*8;
    const float* W = arr ? H1w : Wk;
    unsigned short* dst = (arr ? wfragH : wfragK) + (size_t)s*8;
    #pragma unroll
    for (int e = 0; e < 8; ++e) dst[e] = (unsigned short)f2bf(W[(size_t)(k0+e)*Dd + col]);
}

// ---------------- per-cluster precompute (1000 blocks) + node histogram fused ----------------
__global__ __launch_bounds__(256)
void k_cluster_prep(const float* __restrict__ g, const float* __restrict__ Wq,
                    const float* __restrict__ b_attn,
                    const float* __restrict__ Ws, const float* __restrict__ bs,
                    const float* __restrict__ G1w, const float* __restrict__ G1b,
                    const float* __restrict__ H1b,
                    const int* __restrict__ seg, int* __restrict__ hist,
                    float* __restrict__ qb, float* __restrict__ h_trans,
                    float* __restrict__ cterm){
    int c = blockIdx.x, d = threadIdx.x;
    int gi = c*256 + d;
    if (gi < Nn) atomicAdd(&hist[seg[gi]*PAD], 1);
    __shared__ float gL[Dd], htL[Dd];
    gL[d] = g[(size_t)c*Dd + d];
    __syncthreads();
    float aq = b_attn[d], as = bs[d];
    #pragma unroll 4
    for (int k = 0; k < Dd; ++k){
        float gv = gL[k];
        aq = fmaf(gv, Wq[k*Dd + d], aq);
        as = fmaf(gv, Ws[k*Dd + d], as);
    }
    qb[(size_t)c*Dd + d] = aq;
    float ht = tanhf(as);
    h_trans[(size_t)c*Dd + d] = ht;
    htL[d] = ht;
    __syncthreads();
    float ac = H1b[d] + G1b[d];
    #pragma unroll 4
    for (int k = 0; k < Dd; ++k) ac = fmaf(htL[k], G1w[k*Dd + d], ac);
    cterm[(size_t)c*Dd + d] = ac;
}

// ---------------- counting sort: scan + scatter (padded counters) ----------------
__global__ void k_scan(const int* __restrict__ hist, int* __restrict__ offs, int* __restrict__ cursor){
    __shared__ int sc[1024];
    int t = threadIdx.x;
    int v = (t < Cc) ? hist[t*PAD] : 0;
    sc[t] = v;
    __syncthreads();
    for (int off = 1; off < 1024; off <<= 1){
        int add = (t >= off) ? sc[t - off] : 0;
        __syncthreads();
        sc[t] += add;
        __syncthreads();
    }
    if (t < Cc){
        int excl = sc[t] - v;
        offs[t] = excl;
        cursor[t*PAD] = excl;
    }
}
__global__ void k_scatter(const int* __restrict__ seg, int* __restrict__ cursor, int* __restrict__ order){
    int i = blockIdx.x*256 + threadIdx.x;
    if (i < Nn){
        int p = atomicAdd(&cursor[seg[i]*PAD], 1);
        order[p] = i;
    }
}

// ================= fused score+merge GEMM, swapped operands, two W-passes per chunk =================
// 6250 blocks x 512 threads, 32 nodes/block. D layout: row=node, col=lane&31 -> coalesced epilogues.
// W fragments burst-loaded from the L2-resident table per pass (16 x dwordx4, 64 VGPR, reused),
// so peak register pressure stays ~115 (NO spills). k-loop: 1 ds_read + 1 MFMA, zero VMEM waits.
__global__ __launch_bounds__(512, 2)
void k_gemm4(const float* __restrict__ h, const unsigned short* __restrict__ wfrag,
             const int* __restrict__ seg, const float* __restrict__ qb,
             const float* __restrict__ w_score, const float* __restrict__ b_score,
             const float* __restrict__ cterm, const float* __restrict__ h_trans,
             float* __restrict__ e, float* __restrict__ out){
    __shared__ __align__(16) char Al[16384];    // 32 nodes x 512B bf16, XOR-swizzled
    __shared__ float sPart[32][8];
    __shared__ int segL[32];

    int tid = threadIdx.x;
    int w = tid >> 6, l = tid & 63;
    int lCol = l & 31, hiK = l >> 5;
    int rowBase = blockIdx.x * 32;

    // ---- stage A tile: 4 float4 loads, fp32->bf16 pack, swizzled LDS writes ----
    {
        const float4* hv = reinterpret_cast<const float4*>(h + (size_t)rowBase * Dd);
        float4 v[4];
        #pragma unroll
        for (int j = 0; j < 4; ++j) v[j] = hv[j*512 + tid];
        if (tid < 32) segL[tid] = seg[rowBase + tid];
        #pragma unroll
        for (int j = 0; j < 4; ++j){
            int f = j*512 + tid;
            int row = f >> 6;
            unsigned long long pk = (unsigned long long)f2bf(v[j].x)
                                  | ((unsigned long long)f2bf(v[j].y) << 16)
                                  | ((unsigned long long)f2bf(v[j].z) << 32)
                                  | ((unsigned long long)f2bf(v[j].w) << 48);
            int byte = (row*512 + (f & 63)*8) ^ ((row & 15) << 4);
            *reinterpret_cast<unsigned long long*>(Al + byte) = pk;
        }
    }
    __syncthreads();   // A ready

    int hOff = lCol*512;               // lane&31 = node row of the A fragment
    int swzK = (lCol & 15) << 4;
    const char* wfb = reinterpret_cast<const char*>(wfrag);

    // ================== PASS 1: score (Wk, ct = w) ==================
    {
        bf16x8 wF[16];
        #pragma unroll
        for (int kk = 0; kk < 16; ++kk)
            wF[kk] = *reinterpret_cast<const bf16x8*>(wfb + (size_t)((w*16 + kk)*64 + l)*16);

        f32x16 acc;
        #pragma unroll
        for (int i = 0; i < 16; ++i) acc[i] = 0.f;
        #pragma unroll
        for (int kk = 0; kk < 16; ++kk){
            bf16x8 hF = *reinterpret_cast<const bf16x8*>(Al + ((hOff + kk*32 + hiK*16) ^ swzK));
            acc = __builtin_amdgcn_mfma_f32_32x32x16_bf16(hF, wF[kk], acc, 0, 0, 0);
        }

        float wsc = w_score[w*32 + lCol];
        #pragma unroll
        for (int i = 0; i < 16; ++i){
            int r = (i&3) + 8*(i>>2) + 4*hiK;
            float q = qb[(size_t)segL[r]*Dd + w*32 + lCol];
            float t = exp2f(LOG2E2*(acc[i] + q));
            float p = (t - 1.f)*rcp_(t + 1.f)*wsc;
            p += __shfl_xor(p, 1);
            p += __shfl_xor(p, 2);
            p += __shfl_xor(p, 4);
            p += __shfl_xor(p, 8);
            p += __shfl_xor(p, 16);
            if (lCol == 0) sPart[r][w] = p;
        }
    }

    // ================== PASS 2: merge (H1w, ct = w+8) ==================
    {
        bf16x8 wF[16];
        #pragma unroll
        for (int kk = 0; kk < 16; ++kk)
            wF[kk] = *reinterpret_cast<const bf16x8*>(wfb + (size_t)(((w+8)*16 + kk)*64 + l)*16);

        f32x16 acc;
        #pragma unroll
        for (int i = 0; i < 16; ++i) acc[i] = 0.f;
        #pragma unroll
        for (int kk = 0; kk < 16; ++kk){
            bf16x8 hF = *reinterpret_cast<const bf16x8*>(Al + ((hOff + kk*32 + hiK*16) ^ swzK));
            acc = __builtin_amdgcn_mfma_f32_32x32x16_bf16(hF, wF[kk], acc, 0, 0, 0);
        }

        #pragma unroll
        for (int i = 0; i < 16; ++i){
            int r = (i&3) + 8*(i>>2) + 4*hiK;
            int sgt = segL[r];
            size_t tb = (size_t)sgt*Dd + w*32 + lCol;
            float c4 = cterm[tb];
            float t4 = h_trans[tb];
            unsigned short hb = *reinterpret_cast<const unsigned short*>(
                Al + ((r*512 + (w*32 + lCol)*2) ^ ((r & 15) << 4)));
            float hval = bf2f(hb);
            float z = rcp_(1.f + exp2f(-LOG2E*(acc[i] + c4)));
            out[(size_t)(rowBase + r)*Dd + w*32 + lCol] = fmaf(z, t4 - hval, hval);
        }
    }

    __syncthreads();   // sPart complete
    if (tid < 32){
        float s = sPart[tid][0] + sPart[tid][1] + sPart[tid][2] + sPart[tid][3]
                + sPart[tid][4] + sPart[tid][5] + sPart[tid][6] + sPart[tid][7] + b_score[0];
        e[rowBase + tid] = exp2f(LOG2E * s);   // unshifted exp: |s| small, ratio == ref
    }
}

// ---------------- per-cluster ctx partials: 4 chunk-blocks per cluster, no atomics ----------------
__global__ __launch_bounds__(256)
void k_ctx(const float* __restrict__ h, const float* __restrict__ e,
           const int* __restrict__ order, const int* __restrict__ hist,
           const int* __restrict__ offs,
           float* __restrict__ ctxPart, float* __restrict__ denPart){
    int b = blockIdx.x;
    int c = b >> 2, q = b & 3;
    int cnt = hist[c*PAD], start0 = offs[c];
    int c0 = (cnt * q) >> 2, c1 = (cnt * (q+1)) >> 2;
    int n = c1 - c0;
    int start = start0 + c0;
    int t = threadIdx.x;
    __shared__ int idxL[512];
    __shared__ float eL[512];
    __shared__ float redL[4][256];
    __shared__ float dsum[4];
    int r4 = t >> 6;
    int col4 = (t & 63) << 2;
    float ax = 0.f, ay = 0.f, az = 0.f, aw = 0.f;
    float dpart = 0.f;
    for (int base = 0; base < n; base += 512){
        int m = min(512, n - base);
        for (int i = t; i < m; i += 256){
            int nd = order[start + base + i];
            idxL[i] = nd;
            float ev = e[nd];
            eL[i] = ev;
            dpart += ev;
        }
        __syncthreads();
        #pragma unroll 4
        for (int i = r4; i < m; i += 4){
            float ev = eL[i];
            float4 hv = *reinterpret_cast<const float4*>(h + (size_t)idxL[i]*Dd + col4);
            ax = fmaf(ev, hv.x, ax);
            ay = fmaf(ev, hv.y, ay);
            az = fmaf(ev, hv.z, az);
            aw = fmaf(ev, hv.w, aw);
        }
        __syncthreads();
    }
    *reinterpret_cast<float4*>(&redL[r4][col4]) = (float4){ax, ay, az, aw};
    #pragma unroll
    for (int off = 1; off < 64; off <<= 1) dpart += __shfl_xor(dpart, off);
    if ((t & 63) == 0) dsum[r4] = dpart;
    __syncthreads();
    if (t < 256){
        float s = redL[0][t] + redL[1][t] + redL[2][t] + redL[3][t];
        ctxPart[((size_t)c*4 + q)*Dd + t] = s;
    }
    if (t == 0) denPart[b] = dsum[0] + dsum[1] + dsum[2] + dsum[3];
}

// ---------------- virtual-node side (1 cluster/block) ----------------
__global__ __launch_bounds__(256)
void k_vn(const float* __restrict__ ctxPart, const float* __restrict__ denPart,
          const float* __restrict__ g_hat,
          const float* __restrict__ Wv, const float* __restrict__ bv,
          const float* __restrict__ H2w, const float* __restrict__ H2b,
          const float* __restrict__ G2w, const float* __restrict__ G2b,
          float* __restrict__ out){
    int c = blockIdx.x, d = threadIdx.x;
    __shared__ float cL[Dd], gtL[Dd], ghL[Dd];
    float den = denPart[c*4] + denPart[c*4+1] + denPart[c*4+2] + denPart[c*4+3];
    float inv = (den > 0.f) ? 1.f/den : 0.f;
    float num = ctxPart[((size_t)c*4 + 0)*Dd + d] + ctxPart[((size_t)c*4 + 1)*Dd + d]
              + ctxPart[((size_t)c*4 + 2)*Dd + d] + ctxPart[((size_t)c*4 + 3)*Dd + d];
    cL[d]  = num * inv;
    ghL[d] = g_hat[(size_t)c*Dd + d];
    __syncthreads();
    float a1 = bv[d];
    #pragma unroll 4
    for (int k = 0; k < Dd; ++k) a1 = fmaf(cL[k], Wv[k*Dd + d], a1);
    float gt = tanhf(a1);
    gtL[d] = gt;
    __syncthreads();
    float a2 = H2b[d] + G2b[d];
    #pragma unroll 4
    for (int k = 0; k < Dd; ++k){
        a2 = fmaf(gtL[k], H2w[k*Dd + d], a2);
        a2 = fmaf(ghL[k], G2w[k*Dd + d], a2);
    }
    float z = 1.f / (1.f + expf(-a2));
    out[(size_t)(Nn + c)*Dd + d] = (1.f - z)*gt + z*ghL[d];
}

extern "C" void kernel_launch(void* const* d_in, const int* in_sizes, int n_in,
                              void* d_out, int out_size, void* d_ws, size_t ws_size,
                              hipStream_t stream){
    const float* h       = (const float*)d_in[0];
    const float* g       = (const float*)d_in[1];
    const float* g_hat   = (const float*)d_in[2];
    const int*   seg     = (const int*)  d_in[3];
    const float* Wq      = (const float*)d_in[4];
    const float* Wk      = (const float*)d_in[5];
    const float* b_attn  = (const float*)d_in[6];
    const float* w_score = (const float*)d_in[7];
    const float* b_score = (const float*)d_in[8];
    const float* Wv      = (const float*)d_in[9];
    const float* bv      = (const float*)d_in[10];
    const float* Ws      = (const float*)d_in[11];
    const float* bs      = (const float*)d_in[12];
    const float* H1w     = (const float*)d_in[13];
    const float* H1b     = (const float*)d_in[14];
    const float* G1w     = (const float*)d_in[15];
    const float* G1b     = (const float*)d_in[16];
    const float* H2w     = (const float*)d_in[17];
    const float* H2b     = (const float*)d_in[18];
    const float* G2w     = (const float*)d_in[19];
    const float* G2b     = (const float*)d_in[20];
    float* out = (float*)d_out;

    char* ws = (char*)d_ws;
    unsigned short* wfragK = (unsigned short*)(ws + 0);      //   131,072 B  (ct 0..7)
    unsigned short* wfragH = (unsigned short*)(ws + 131072); //   131,072 B  (ct 8..15, contiguous)
    float* qb      = (float*)(ws +  262144);                 // 1,024,000 B
    float* h_trans = (float*)(ws + 1286144);                 // 1,024,000 B
    float* cterm   = (float*)(ws + 2310144);                 // 1,024,000 B
    float* e       = (float*)(ws + 3334144);                 //   800,000 B
    int*   order   = (int*)  (ws + 4134144);                 //   800,000 B
    int*   hist    = (int*)  (ws + 4934144);                 //    64,000 B (padded x16)
    int*   offs    = (int*)  (ws + 4998144);                 //     4,000 B
    int*   cursor  = (int*)  (ws + 5002144);                 //    64,000 B (padded x16)
    float* ctxPart = (float*)(ws + 5066144);                 // 4,096,000 B
    float* denPart = (float*)(ws + 9162144);                 //    16,000 B

    hipLaunchKernelGGL(k_prep, dim3(64), dim3(256), 0, stream, Wk, H1w, wfragK, wfragH, hist);
    hipLaunchKernelGGL(k_cluster_prep, dim3(Cc), dim3(256), 0, stream,
                       g, Wq, b_attn, Ws, bs, G1w, G1b, H1b, seg, hist, qb, h_trans, cterm);
    hipLaunchKernelGGL(k_scan, dim3(1), dim3(1024), 0, stream, hist, offs, cursor);
    hipLaunchKernelGGL(k_scatter, dim3((Nn + 255)/256), dim3(256), 0, stream, seg, cursor, order);
    hipLaunchKernelGGL(k_gemm4, dim3(NCH4), dim3(512), 0, stream,
                       h, wfragK, seg, qb, w_score, b_score, cterm, h_trans, e, out);
    hipLaunchKernelGGL(k_ctx, dim3(Cc*4), dim3(256), 0, stream, h, e, order, hist, offs, ctxPart, denPart);
    hipLaunchKernelGGL(k_vn, dim3(Cc), dim3(256), 0, stream,
                       ctxPart, denPart, g_hat, Wv, bv, H2w, H2b, G2w, G2b, out);
}